// Round 1
// baseline (47.049 us; speedup 1.0000x reference)
//
#include <hip/hip_runtime.h>

#define NCOLORS 10
#define EPS 1e-8f
#define HW 4096
#define S_DIM 16

__global__ __launch_bounds__(1024)
void color_entropy_kernel(const float* __restrict__ attn,   // [B, S, HW]
                          const int* __restrict__ grids,    // [B, HW]
                          float* __restrict__ out,          // [1]
                          float inv_BS)
{
    const int b    = blockIdx.x;
    const int tid  = threadIdx.x;
    const int lane = tid & 63;
    const int wave = tid >> 6;          // wave == s  (16 waves per block)

    __shared__ int   lgrid[HW];
    __shared__ float wsum[S_DIM];

    // Stage grids[b] into LDS: 1024 threads x int4 = 4096 ints, coalesced.
    const int4* g4 = reinterpret_cast<const int4*>(grids + (size_t)b * HW);
    reinterpret_cast<int4*>(lgrid)[tid] = g4[tid];
    __syncthreads();

    // Each wave streams one attn row: 4096 floats = 16 iters of float4/lane.
    const float4* a4 =
        reinterpret_cast<const float4*>(attn + ((size_t)b * S_DIM + wave) * HW);
    const int4* lg4 = reinterpret_cast<const int4*>(lgrid);

    float bins[NCOLORS];
#pragma unroll
    for (int c = 0; c < NCOLORS; ++c) bins[c] = 0.0f;

#pragma unroll
    for (int it = 0; it < HW / 256; ++it) {
        const int idx = it * 64 + lane;       // float4 index
        const float4 a = a4[idx];
        const int4   g = lg4[idx];
#pragma unroll
        for (int c = 0; c < NCOLORS; ++c) {   // compile-time bin index only
            bins[c] += (g.x == c) ? a.x : 0.0f;
            bins[c] += (g.y == c) ? a.y : 0.0f;
            bins[c] += (g.z == c) ? a.z : 0.0f;
            bins[c] += (g.w == c) ? a.w : 0.0f;
        }
    }

    // Butterfly reduce each bin across the 64-lane wave (all lanes end full).
#pragma unroll
    for (int c = 0; c < NCOLORS; ++c) {
#pragma unroll
        for (int off = 32; off >= 1; off >>= 1)
            bins[c] += __shfl_xor(bins[c], off, 64);
    }

    // Entropy for this (b, s) — computed redundantly on all lanes.
    float total = 0.0f;
#pragma unroll
    for (int c = 0; c < NCOLORS; ++c) total += bins[c];
    const float inv = 1.0f / (total + EPS);
    float ent = 0.0f;
#pragma unroll
    for (int c = 0; c < NCOLORS; ++c) {
        const float p = bins[c] * inv;
        ent -= p * __logf(p + EPS);
    }

    if (lane == 0) wsum[wave] = ent;
    __syncthreads();

    if (tid == 0) {
        float bs = 0.0f;
#pragma unroll
        for (int s = 0; s < S_DIM; ++s) bs += wsum[s];
        atomicAdd(out, bs * inv_BS);
    }
}

extern "C" void kernel_launch(void* const* d_in, const int* in_sizes, int n_in,
                              void* d_out, int out_size, void* d_ws, size_t ws_size,
                              hipStream_t stream) {
    const float* attn  = (const float*)d_in[0];
    const int*   grids = (const int*)d_in[1];
    float*       out   = (float*)d_out;

    const int B = in_sizes[1] / HW;               // 512
    const float inv_BS = 1.0f / (float)(B * S_DIM);

    hipMemsetAsync(out, 0, sizeof(float) * out_size, stream);
    color_entropy_kernel<<<B, 1024, 0, stream>>>(attn, grids, out, inv_BS);
}

// Round 2
// 41.958 us; speedup vs baseline: 1.1213x; 1.1213x over previous
//
#include <hip/hip_runtime.h>

#define NCOLORS 10
#define EPS 1e-8f
#define HW 4096
#define S_DIM 16
#define WAVES 16
#define THREADS (WAVES * 64)
#define K_PER_WAVE (HW / WAVES)          // 256
#define ITERS (K_PER_WAVE / 32)          // 8 MFMAs per wave

typedef __bf16 bf16x8 __attribute__((ext_vector_type(8)));
typedef float  f32x4  __attribute__((ext_vector_type(4)));

__global__ __launch_bounds__(THREADS)
void color_entropy_mfma(const float* __restrict__ attn,   // [B, S, HW]
                       const int* __restrict__ grids,     // [B, HW]
                       float* __restrict__ out,           // [1]
                       float inv_BS)
{
    const int b    = blockIdx.x;
    const int tid  = threadIdx.x;
    const int lane = tid & 63;
    const int wave = tid >> 6;
    const int sc   = lane & 15;     // A-row (s) AND B-col (color) index
    const int grp  = lane >> 4;     // k sub-group within the 32-wide K tile

    // A fragment source: attn[b][sc][k0 + grp*8 .. +7]  (8 consecutive f32)
    const float* aBase = attn + ((size_t)b * S_DIM + sc) * HW + grp * 8;
    // B (one-hot) source: grids[b][k0 + grp*8 .. +7]
    const int*   gBase = grids + (size_t)b * HW + grp * 8;

    const __bf16 ONE  = (__bf16)1.0f;
    const __bf16 ZER  = (__bf16)0.0f;

    f32x4 acc = {0.f, 0.f, 0.f, 0.f};

#pragma unroll 4
    for (int it = 0; it < ITERS; ++it) {
        const int k0 = wave * K_PER_WAVE + it * 32;
        const float4 f0 = *reinterpret_cast<const float4*>(aBase + k0);
        const float4 f1 = *reinterpret_cast<const float4*>(aBase + k0 + 4);
        const int4   g0 = *reinterpret_cast<const int4*>(gBase + k0);
        const int4   g1 = *reinterpret_cast<const int4*>(gBase + k0 + 4);

        bf16x8 a;
        a[0] = (__bf16)f0.x; a[1] = (__bf16)f0.y;
        a[2] = (__bf16)f0.z; a[3] = (__bf16)f0.w;
        a[4] = (__bf16)f1.x; a[5] = (__bf16)f1.y;
        a[6] = (__bf16)f1.z; a[7] = (__bf16)f1.w;

        bf16x8 oh;
        oh[0] = (g0.x == sc) ? ONE : ZER;
        oh[1] = (g0.y == sc) ? ONE : ZER;
        oh[2] = (g0.z == sc) ? ONE : ZER;
        oh[3] = (g0.w == sc) ? ONE : ZER;
        oh[4] = (g1.x == sc) ? ONE : ZER;
        oh[5] = (g1.y == sc) ? ONE : ZER;
        oh[6] = (g1.z == sc) ? ONE : ZER;
        oh[7] = (g1.w == sc) ? ONE : ZER;

        acc = __builtin_amdgcn_mfma_f32_16x16x32_bf16(a, oh, acc, 0, 0, 0);
    }

    // D layout: D[row = grp*4 + j][col = sc] = acc[j]   (verified C/D map)
    __shared__ float red[WAVES][256];
#pragma unroll
    for (int j = 0; j < 4; ++j)
        red[wave][(grp * 4 + j) * 16 + sc] = acc[j];
    __syncthreads();

    // Sum the 16 partial C tiles: thread t owns cell t (row t/16, col t%16).
    if (tid < 256) {
        float s = 0.f;
#pragma unroll
        for (int w = 0; w < WAVES; ++w) s += red[w][tid];
        red[0][tid] = s;
    }
    __syncthreads();

    __shared__ float ent16[S_DIM];
    if (tid < S_DIM) {
        float bins[NCOLORS];
        float tot = 0.f;
#pragma unroll
        for (int c = 0; c < NCOLORS; ++c) {
            bins[c] = red[0][tid * 16 + c];
            tot += bins[c];
        }
        const float inv = 1.0f / (tot + EPS);
        float e = 0.f;
#pragma unroll
        for (int c = 0; c < NCOLORS; ++c) {
            const float p = bins[c] * inv;
            e -= p * __logf(p + EPS);
        }
        ent16[tid] = e;
    }
    __syncthreads();

    if (tid == 0) {
        float s = 0.f;
#pragma unroll
        for (int i = 0; i < S_DIM; ++i) s += ent16[i];
        atomicAdd(out, s * inv_BS);
    }
}

extern "C" void kernel_launch(void* const* d_in, const int* in_sizes, int n_in,
                              void* d_out, int out_size, void* d_ws, size_t ws_size,
                              hipStream_t stream) {
    const float* attn  = (const float*)d_in[0];
    const int*   grids = (const int*)d_in[1];
    float*       out   = (float*)d_out;

    const int B = in_sizes[1] / HW;               // 512
    const float inv_BS = 1.0f / (float)(B * S_DIM);

    hipMemsetAsync(out, 0, sizeof(float) * out_size, stream);
    color_entropy_mfma<<<B, THREADS, 0, stream>>>(attn, grids, out, inv_BS);
}

// Round 3
// 37.048 us; speedup vs baseline: 1.2699x; 1.1325x over previous
//
#include <hip/hip_runtime.h>

#define NCOLORS 10
#define EPS 1e-8f
#define HW 4096
#define S_DIM 16
#define WAVES 8
#define THREADS (WAVES * 64)             // 512
#define K_PER_WAVE (HW / WAVES)          // 512
#define ITERS (K_PER_WAVE / 32)          // 16 MFMAs per wave

typedef __bf16 bf16x8 __attribute__((ext_vector_type(8)));
typedef float  f32x4  __attribute__((ext_vector_type(4)));

__global__ __launch_bounds__(THREADS, 4)   // VGPR <= 128 -> 2 blocks/CU co-resident
void color_entropy_mfma(const float* __restrict__ attn,   // [B, S, HW]
                        const int* __restrict__ grids,    // [B, HW]
                        float* __restrict__ out,          // [1]
                        float inv_BS)
{
    const int b    = blockIdx.x;
    const int tid  = threadIdx.x;
    const int lane = tid & 63;
    const int wave = tid >> 6;      // 0..7
    const int sc   = lane & 15;     // A-row (s) AND B-col (color) index
    const int grp  = lane >> 4;     // k sub-group within the 32-wide K tile

    const float* aBase = attn + ((size_t)b * S_DIM + sc) * HW + grp * 8;
    const int*   gBase = grids + (size_t)b * HW + grp * 8;

    const __bf16 ONE  = (__bf16)1.0f;
    const __bf16 ZER  = (__bf16)0.0f;

    f32x4 acc = {0.f, 0.f, 0.f, 0.f};

#pragma unroll 2
    for (int it = 0; it < ITERS; ++it) {
        const int k0 = wave * K_PER_WAVE + it * 32;
        const float4 f0 = *reinterpret_cast<const float4*>(aBase + k0);
        const float4 f1 = *reinterpret_cast<const float4*>(aBase + k0 + 4);
        const int4   g0 = *reinterpret_cast<const int4*>(gBase + k0);
        const int4   g1 = *reinterpret_cast<const int4*>(gBase + k0 + 4);

        bf16x8 a;
        a[0] = (__bf16)f0.x; a[1] = (__bf16)f0.y;
        a[2] = (__bf16)f0.z; a[3] = (__bf16)f0.w;
        a[4] = (__bf16)f1.x; a[5] = (__bf16)f1.y;
        a[6] = (__bf16)f1.z; a[7] = (__bf16)f1.w;

        bf16x8 oh;
        oh[0] = (g0.x == sc) ? ONE : ZER;
        oh[1] = (g0.y == sc) ? ONE : ZER;
        oh[2] = (g0.z == sc) ? ONE : ZER;
        oh[3] = (g0.w == sc) ? ONE : ZER;
        oh[4] = (g1.x == sc) ? ONE : ZER;
        oh[5] = (g1.y == sc) ? ONE : ZER;
        oh[6] = (g1.z == sc) ? ONE : ZER;
        oh[7] = (g1.w == sc) ? ONE : ZER;

        acc = __builtin_amdgcn_mfma_f32_16x16x32_bf16(a, oh, acc, 0, 0, 0);
    }

    // D layout: D[row = grp*4 + j][col = sc] = acc[j]
    __shared__ float red[WAVES][256];
#pragma unroll
    for (int j = 0; j < 4; ++j)
        red[wave][(grp * 4 + j) * 16 + sc] = acc[j];
    __syncthreads();

    if (tid < 256) {
        float s = 0.f;
#pragma unroll
        for (int w = 0; w < WAVES; ++w) s += red[w][tid];
        red[0][tid] = s;
    }
    __syncthreads();

    __shared__ float ent16[S_DIM];
    if (tid < S_DIM) {
        float bins[NCOLORS];
        float tot = 0.f;
#pragma unroll
        for (int c = 0; c < NCOLORS; ++c) {
            bins[c] = red[0][tid * 16 + c];
            tot += bins[c];
        }
        const float inv = 1.0f / (tot + EPS);
        float e = 0.f;
#pragma unroll
        for (int c = 0; c < NCOLORS; ++c) {
            const float p = bins[c] * inv;
            e -= p * __logf(p + EPS);
        }
        ent16[tid] = e;
    }
    __syncthreads();

    if (tid == 0) {
        float s = 0.f;
#pragma unroll
        for (int i = 0; i < S_DIM; ++i) s += ent16[i];
        atomicAdd(out, s * inv_BS);
    }
}

extern "C" void kernel_launch(void* const* d_in, const int* in_sizes, int n_in,
                              void* d_out, int out_size, void* d_ws, size_t ws_size,
                              hipStream_t stream) {
    const float* attn  = (const float*)d_in[0];
    const int*   grids = (const int*)d_in[1];
    float*       out   = (float*)d_out;

    const int B = in_sizes[1] / HW;               // 512
    const float inv_BS = 1.0f / (float)(B * S_DIM);

    hipMemsetAsync(out, 0, sizeof(float) * out_size, stream);
    color_entropy_mfma<<<B, THREADS, 0, stream>>>(attn, grids, out, inv_BS);
}